// Round 4
// baseline (283.904 us; speedup 1.0000x reference)
//
#include <hip/hip_runtime.h>
#include <hip/hip_bf16.h>

typedef __attribute__((ext_vector_type(8))) short bf16x8;
typedef __attribute__((ext_vector_type(4))) float f32x4;

#define L_SEQ 512
#define N_IN 12
#define S_DIM 128
#define M_OUT 12

// RNE f32->bf16 (cold paths)
__device__ inline short f2bf(float f) {
    union { float f; unsigned u; } q; q.f = f;
    unsigned r = (q.u + 0x7fffu + ((q.u >> 16) & 1u)) >> 16;
    return (short)r;
}

// packed f32x2 -> 2xbf16 in one dword (low=first arg). Verified m214v22.
__device__ inline unsigned cvtpk(float lo, float hi) {
    unsigned r;
    asm("v_cvt_pk_bf16_f32 %0, %1, %2" : "=v"(r) : "v"(lo), "v"(hi));
    return r;
}

// s-permutation: B-slot (kt, q, j) holds state row s = 32*kt + 16*(j>>2) + 4*q + (j&3).
// This makes D-slot (rt=2kt+(j>>2), reg=j&3) of the SAME lane be the next-step B-slot.
__device__ inline int s_perm(int kt, int q, int j) {
    return 32 * kt + 16 * (j >> 2) + 4 * q + (j & 3);
}

__global__ __launch_bounds__(64, 1)
void elman_kernel(const float* __restrict__ x,
                  const float* __restrict__ a0,
                  const float* __restrict__ U_w,
                  const float* __restrict__ U_b,
                  const float* __restrict__ W_w,
                  const float* __restrict__ W_b,
                  const float* __restrict__ V_w,
                  const float* __restrict__ V_b,
                  float* __restrict__ out)
{
    const int l  = threadIdx.x & 63;
    const int n  = l & 15;          // batch col (B/D) and A-row index
    const int q  = l >> 4;          // lane group
    const int b0 = blockIdx.x * 16;
    const int row = b0 + n;         // this lane's batch row
    const bool qodd = (q & 1);

    // ---- W^T as A-fragments: wf[rt][kt], A[m=n][k-slot(q,j)] = W_w[s_perm(kt,q,j)][rt*16+n]
    bf16x8 wf[8][4];
    #pragma unroll
    for (int rt = 0; rt < 8; ++rt)
        #pragma unroll
        for (int kt = 0; kt < 4; ++kt)
            #pragma unroll
            for (int j = 0; j < 8; ++j)
                wf[rt][kt][j] = f2bf(W_w[(size_t)s_perm(kt, q, j) * S_DIM + rt * 16 + n]);

    // ---- U^T as A-fragments (single K=32 tile, physical k = q*8+j):
    //      k<12 -> U_w[k][c]; k==12 -> fused bias (x slot carries 1.0); else 0.
    bf16x8 uf[8];
    #pragma unroll
    for (int rt = 0; rt < 8; ++rt) {
        const int c = rt * 16 + n;
        #pragma unroll
        for (int j = 0; j < 8; ++j) {
            const int k = q * 8 + j;
            float v;
            if (k < N_IN)       v = U_w[(size_t)k * S_DIM + c];
            else if (k == N_IN) v = W_b[c] + U_b[c];
            else                v = 0.f;
            uf[rt][j] = f2bf(v);
        }
    }

    // ---- state init from a0 (permuted layout) ----
    bf16x8 st[4];
    #pragma unroll
    for (int kt = 0; kt < 4; ++kt) {
        const float4 va = *(const float4*)&a0[(size_t)row * S_DIM + 32 * kt + 4 * q];
        const float4 vb = *(const float4*)&a0[(size_t)row * S_DIM + 32 * kt + 16 + 4 * q];
        st[kt][0] = f2bf(va.x); st[kt][1] = f2bf(va.y);
        st[kt][2] = f2bf(va.z); st[kt][3] = f2bf(va.w);
        st[kt][4] = f2bf(vb.x); st[kt][5] = f2bf(vb.y);
        st[kt][6] = f2bf(vb.z); st[kt][7] = f2bf(vb.w);
    }

    // ---- x stream: lane supplies B k-slots q*8+j -> x[row][t][q*8+j] (only q<2 used; q>=2 A=0)
    const float* xpA = x + (size_t)row * L_SEQ * N_IN + (q & 1) * 8;
    const float* xpB = xpA + (qodd ? 0 : 4);   // qodd's second half is dummy (overwritten)
    float4 xa0 = *(const float4*)(xpA + 0 * N_IN), xb0 = *(const float4*)(xpB + 0 * N_IN);
    float4 xa1 = *(const float4*)(xpA + 1 * N_IN), xb1 = *(const float4*)(xpB + 1 * N_IN);
    float4 xa2 = *(const float4*)(xpA + 2 * N_IN), xb2 = *(const float4*)(xpB + 2 * N_IN);
    float4 xa3 = *(const float4*)(xpA + 3 * N_IN), xb3 = *(const float4*)(xpB + 3 * N_IN);

#define STEP(XA, XB, TNEXT) do {                                                       \
    union { unsigned u[4]; bf16x8 v; } xu_;                                            \
    xu_.u[0] = cvtpk(XA.x, XA.y);                                                      \
    xu_.u[1] = cvtpk(XA.z, XA.w);                                                      \
    xu_.u[2] = qodd ? 0x00003F80u : cvtpk(XB.x, XB.y);  /* k==12 -> bf16(1.0) */       \
    xu_.u[3] = qodd ? 0u          : cvtpk(XB.z, XB.w);                                 \
    const bf16x8 xf = xu_.v;                                                           \
    const int tl_ = ((TNEXT) < L_SEQ) ? (TNEXT) : (L_SEQ - 1);                         \
    XA = *(const float4*)(xpA + (size_t)tl_ * N_IN);                                   \
    XB = *(const float4*)(xpB + (size_t)tl_ * N_IN);                                   \
    f32x4 acc[8];                                                                      \
    _Pragma("unroll")                                                                  \
    for (int rt = 0; rt < 8; ++rt) {                                                   \
        f32x4 z = {0.f, 0.f, 0.f, 0.f};                                                \
        acc[rt] = __builtin_amdgcn_mfma_f32_16x16x32_bf16(uf[rt], xf, z, 0, 0, 0);     \
    }                                                                                  \
    _Pragma("unroll")                                                                  \
    for (int kt = 0; kt < 4; ++kt)                                                     \
        _Pragma("unroll")                                                              \
        for (int rt = 0; rt < 8; ++rt)                                                 \
            acc[rt] = __builtin_amdgcn_mfma_f32_16x16x32_bf16(wf[rt][kt], st[kt],      \
                                                              acc[rt], 0, 0, 0);       \
    _Pragma("unroll")                                                                  \
    for (int kt = 0; kt < 4; ++kt) {                                                   \
        union { unsigned u[4]; bf16x8 v; } su_;                                        \
        su_.u[0] = cvtpk(fmaxf(acc[2*kt  ][0], 0.f), fmaxf(acc[2*kt  ][1], 0.f));      \
        su_.u[1] = cvtpk(fmaxf(acc[2*kt  ][2], 0.f), fmaxf(acc[2*kt  ][3], 0.f));      \
        su_.u[2] = cvtpk(fmaxf(acc[2*kt+1][0], 0.f), fmaxf(acc[2*kt+1][1], 0.f));      \
        su_.u[3] = cvtpk(fmaxf(acc[2*kt+1][2], 0.f), fmaxf(acc[2*kt+1][3], 0.f));      \
        st[kt] = su_.v;                                                                \
    }                                                                                  \
} while (0)

    for (int t = 0; t < L_SEQ; t += 4) {
        STEP(xa0, xb0, t + 4);
        STEP(xa1, xb1, t + 5);
        STEP(xa2, xb2, t + 6);
        STEP(xa3, xb3, t + 7);
    }
#undef STEP

    // ---- epilogue: yT = V^T @ aT_L + V_b ----
    {
        f32x4 acc = {0.f, 0.f, 0.f, 0.f};
        #pragma unroll
        for (int kt = 0; kt < 4; ++kt) {
            bf16x8 vf;
            #pragma unroll
            for (int j = 0; j < 8; ++j)
                vf[j] = (n < M_OUT)
                      ? f2bf(V_w[(size_t)s_perm(kt, q, j) * M_OUT + n])
                      : (short)0;
            acc = __builtin_amdgcn_mfma_f32_16x16x32_bf16(vf, st[kt], acc, 0, 0, 0);
        }
        // D: out-dim m = 4*q + reg, batch col = n
        #pragma unroll
        for (int j = 0; j < 4; ++j) {
            const int m = 4 * q + j;
            if (m < M_OUT)
                out[(size_t)row * M_OUT + m] = acc[j] + V_b[m];
        }
    }
}

extern "C" void kernel_launch(void* const* d_in, const int* in_sizes, int n_in,
                              void* d_out, int out_size, void* d_ws, size_t ws_size,
                              hipStream_t stream) {
    const float* x   = (const float*)d_in[0];
    const float* a0  = (const float*)d_in[1];
    const float* U_w = (const float*)d_in[2];
    const float* U_b = (const float*)d_in[3];
    const float* W_w = (const float*)d_in[4];
    const float* W_b = (const float*)d_in[5];
    const float* V_w = (const float*)d_in[6];
    const float* V_b = (const float*)d_in[7];
    float* out = (float*)d_out;

    hipLaunchKernelGGL(elman_kernel, dim3(4096 / 16), dim3(64), 0, stream,
                       x, a0, U_w, U_b, W_w, W_b, V_w, V_b, out);
}

// Round 5
// 135.651 us; speedup vs baseline: 2.0929x; 2.0929x over previous
//
#include <hip/hip_runtime.h>
#include <hip/hip_bf16.h>

typedef __attribute__((ext_vector_type(8))) short bf16x8;
typedef __attribute__((ext_vector_type(4))) float f32x4;

#define L_SEQ 512
#define N_IN 12
#define S_DIM 128
#define M_OUT 12
#define LPAD 40           // shorts per n-row in exchange buffer (80B -> <=2-way banks)
#define KT_STRIDE (16*LPAD)

// RNE f32->bf16 (cold paths)
__device__ inline short f2bf(float f) {
    union { float f; unsigned u; } q; q.f = f;
    unsigned r = (q.u + 0x7fffu + ((q.u >> 16) & 1u)) >> 16;
    return (short)r;
}
// packed f32x2 -> 2xbf16 (RNE), one VALU op
__device__ inline unsigned cvtpk(float lo, float hi) {
    unsigned r;
    asm("v_cvt_pk_bf16_f32 %0, %1, %2" : "=v"(r) : "v"(lo), "v"(hi));
    return r;
}
// B-slot (kt,q,j) holds state row s; D-slot (rt=2kt+(j>>2), reg=j&3) of the same
// lane is the next-step B-slot.  END-TO-END VERIFIED in R4 (absmax 0.0078).
__device__ inline int s_perm(int kt, int q, int j) {
    return 32 * kt + 16 * (j >> 2) + 4 * q + (j & 3);
}
// lgkm-only barrier: does NOT drain vmcnt (keeps x prefetch loads in flight)
__device__ inline void block_sync() {
    asm volatile("s_waitcnt lgkmcnt(0)" ::: "memory");
    __builtin_amdgcn_s_barrier();
}

__global__ __launch_bounds__(256, 1)
void elman_kernel(const float* __restrict__ x,
                  const float* __restrict__ a0,
                  const float* __restrict__ U_w,
                  const float* __restrict__ U_b,
                  const float* __restrict__ W_w,
                  const float* __restrict__ W_b,
                  const float* __restrict__ V_w,
                  const float* __restrict__ V_b,
                  float* __restrict__ out)
{
    // exchange buffers: [buf][kt][n][q*8+j] bf16, row padded to 40 shorts
    __shared__ __align__(16) short stx[2][4 * KT_STRIDE];

    const int tid  = threadIdx.x;
    const int w    = tid >> 6;        // wave 0..3 (one per SIMD)
    const int l    = tid & 63;
    const int n    = l & 15;          // batch col
    const int q    = l >> 4;          // lane group
    const bool qodd = (q & 1);
    const int b0   = blockIdx.x * 16;
    const int row  = b0 + n;

    // ---- step-invariant fragments.  Wave w owns output rows [32w, 32w+32):
    //      rt = 2w+h (h=0,1).  W k-tiles in wave-local order li: physical kt=(w+li)&3.
    bf16x8 wf[2][4]; bf16x8 uf[2];
    #pragma unroll
    for (int h = 0; h < 2; ++h) {
        const int c = (2 * w + h) * 16 + n;
        #pragma unroll
        for (int li = 0; li < 4; ++li) {
            const int kt = (w + li) & 3;
            #pragma unroll
            for (int j = 0; j < 8; ++j)
                wf[h][li][j] = f2bf(W_w[(size_t)s_perm(kt, q, j) * S_DIM + c]);
        }
        #pragma unroll
        for (int j = 0; j < 8; ++j) {
            const int k = q * 8 + j;
            float v;
            if (k < N_IN)       v = U_w[(size_t)k * S_DIM + c];
            else if (k == N_IN) v = W_b[c] + U_b[c];   // bias via x-slot k=12 == 1.0
            else                v = 0.f;
            uf[h][j] = f2bf(v);
        }
    }

    // ---- stage a0 into buf0 in exchange layout ----
    for (int idx = tid; idx < 4 * 16 * 32; idx += 256) {
        const int kt = idx >> 9, r = (idx >> 5) & 15, qj = idx & 31;
        const int s = s_perm(kt, qj >> 3, qj & 7);
        stx[0][kt * KT_STRIDE + r * LPAD + qj] = f2bf(a0[(size_t)(b0 + r) * S_DIM + s]);
    }
    block_sync();

    const int fragoff = n * LPAD + q * 8;
    bf16x8 stOwn = *(const bf16x8*)&stx[0][((w + 0) & 3) * KT_STRIDE + fragoff];
    bf16x8 stf1  = *(const bf16x8*)&stx[0][((w + 1) & 3) * KT_STRIDE + fragoff];
    bf16x8 stf2  = *(const bf16x8*)&stx[0][((w + 2) & 3) * KT_STRIDE + fragoff];
    bf16x8 stf3  = *(const bf16x8*)&stx[0][((w + 3) & 3) * KT_STRIDE + fragoff];

    // ---- x stream (R4-verified): lane supplies B k-slots q*8+j = x[row][t][q*8+j]
    const float* xpA = x + (size_t)row * L_SEQ * N_IN + (q & 1) * 8;
    const float* xpB = xpA + (qodd ? 0 : 4);
    float4 xa0 = *(const float4*)(xpA + 0 * N_IN), xb0 = *(const float4*)(xpB + 0 * N_IN);
    float4 xa1 = *(const float4*)(xpA + 1 * N_IN), xb1 = *(const float4*)(xpB + 1 * N_IN);
    float4 xa2 = *(const float4*)(xpA + 2 * N_IN), xb2 = *(const float4*)(xpB + 2 * N_IN);
    float4 xa3 = *(const float4*)(xpA + 3 * N_IN), xb3 = *(const float4*)(xpB + 3 * N_IN);

#define MAKE_XF(XF, XA, XB) do {                                                       \
    union { unsigned u[4]; bf16x8 v; } xu_;                                            \
    xu_.u[0] = cvtpk(XA.x, XA.y);                                                      \
    xu_.u[1] = cvtpk(XA.z, XA.w);                                                      \
    xu_.u[2] = qodd ? 0x00003F80u : cvtpk(XB.x, XB.y);  /* k==12 -> bf16(1.0) */       \
    xu_.u[3] = qodd ? 0u          : cvtpk(XB.z, XB.w);                                 \
    XF = xu_.v;                                                                        \
} while (0)

    // accU(0) = U . x(0) + bias; then recycle slot0 with x(4)
    f32x4 accU0, accU1;
    {
        bf16x8 xf; MAKE_XF(xf, xa0, xb0);
        f32x4 z = {0.f, 0.f, 0.f, 0.f};
        accU0 = __builtin_amdgcn_mfma_f32_16x16x32_bf16(uf[0], xf, z, 0, 0, 0);
        accU1 = __builtin_amdgcn_mfma_f32_16x16x32_bf16(uf[1], xf, z, 0, 0, 0);
        xa0 = *(const float4*)(xpA + 4 * N_IN);
        xb0 = *(const float4*)(xpB + 4 * N_IN);
    }

    // step TT: consume accU(=U.x(TT)); prepare xf(TT+1) from slot (TT+1)%4, reload
    // that slot with x(TNEXT=TT+5); exchange st(TT+1) via LDS buf[(TT+1)&1].
#define STEP(XA, XB, TT, TNEXT) do {                                                   \
    f32x4 acc0, acc1;                                                                  \
    acc0 = __builtin_amdgcn_mfma_f32_16x16x32_bf16(wf[0][0], stOwn, accU0, 0, 0, 0);   \
    acc1 = __builtin_amdgcn_mfma_f32_16x16x32_bf16(wf[1][0], stOwn, accU1, 0, 0, 0);   \
    acc0 = __builtin_amdgcn_mfma_f32_16x16x32_bf16(wf[0][1], stf1, acc0, 0, 0, 0);     \
    acc1 = __builtin_amdgcn_mfma_f32_16x16x32_bf16(wf[1][1], stf1, acc1, 0, 0, 0);     \
    acc0 = __builtin_amdgcn_mfma_f32_16x16x32_bf16(wf[0][2], stf2, acc0, 0, 0, 0);     \
    acc1 = __builtin_amdgcn_mfma_f32_16x16x32_bf16(wf[1][2], stf2, acc1, 0, 0, 0);     \
    acc0 = __builtin_amdgcn_mfma_f32_16x16x32_bf16(wf[0][3], stf3, acc0, 0, 0, 0);     \
    acc1 = __builtin_amdgcn_mfma_f32_16x16x32_bf16(wf[1][3], stf3, acc1, 0, 0, 0);     \
    /* independent: next-step U.x while W-chain drains */                              \
    {                                                                                  \
        bf16x8 xf_; MAKE_XF(xf_, XA, XB);                                              \
        const int tl_ = ((TNEXT) < L_SEQ) ? (TNEXT) : (L_SEQ - 1);                     \
        XA = *(const float4*)(xpA + (size_t)tl_ * N_IN);                               \
        XB = *(const float4*)(xpB + (size_t)tl_ * N_IN);                               \
        f32x4 z_ = {0.f, 0.f, 0.f, 0.f};                                               \
        accU0 = __builtin_amdgcn_mfma_f32_16x16x32_bf16(uf[0], xf_, z_, 0, 0, 0);      \
        accU1 = __builtin_amdgcn_mfma_f32_16x16x32_bf16(uf[1], xf_, z_, 0, 0, 0);      \
    }                                                                                  \
    /* relu + pack own D tile -> next-step B tile (same-lane, s_perm) */               \
    {                                                                                  \
        union { unsigned u[4]; bf16x8 v; } su_;                                        \
        su_.u[0] = cvtpk(fmaxf(acc0[0], 0.f), fmaxf(acc0[1], 0.f));                    \
        su_.u[1] = cvtpk(fmaxf(acc0[2], 0.f), fmaxf(acc0[3], 0.f));                    \
        su_.u[2] = cvtpk(fmaxf(acc1[0], 0.f), fmaxf(acc1[1], 0.f));                    \
        su_.u[3] = cvtpk(fmaxf(acc1[2], 0.f), fmaxf(acc1[3], 0.f));                    \
        stOwn = su_.v;                                                                 \
    }                                                                                  \
    short* wr_ = &stx[(TT + 1) & 1][w * KT_STRIDE + fragoff];                          \
    *(bf16x8*)wr_ = stOwn;                                                             \
    block_sync();                                                                      \
    const short* rd_ = &stx[(TT + 1) & 1][0];                                          \
    stf1 = *(const bf16x8*)&rd_[((w + 1) & 3) * KT_STRIDE + fragoff];                  \
    stf2 = *(const bf16x8*)&rd_[((w + 2) & 3) * KT_STRIDE + fragoff];                  \
    stf3 = *(const bf16x8*)&rd_[((w + 3) & 3) * KT_STRIDE + fragoff];                  \
} while (0)

    for (int t = 0; t < L_SEQ; t += 4) {
        STEP(xa1, xb1, t + 0, t + 5);
        STEP(xa2, xb2, t + 1, t + 6);
        STEP(xa3, xb3, t + 2, t + 7);
        STEP(xa0, xb0, t + 3, t + 8);
    }
#undef STEP
#undef MAKE_XF

    // ---- epilogue: yT = V^T @ aT_L + V_b.  Wave 0 only (its li order == physical kt).
    if (w == 0) {
        f32x4 acc = {0.f, 0.f, 0.f, 0.f};
        #pragma unroll
        for (int li = 0; li < 4; ++li) {
            bf16x8 vf;
            #pragma unroll
            for (int j = 0; j < 8; ++j)
                vf[j] = (n < M_OUT)
                      ? f2bf(V_w[(size_t)s_perm(li, q, j) * M_OUT + n])
                      : (short)0;
            const bf16x8 stt = (li == 0) ? stOwn : (li == 1) ? stf1 : (li == 2) ? stf2 : stf3;
            acc = __builtin_amdgcn_mfma_f32_16x16x32_bf16(vf, stt, acc, 0, 0, 0);
        }
        #pragma unroll
        for (int j = 0; j < 4; ++j) {
            const int m = 4 * q + j;
            if (m < M_OUT)
                out[(size_t)row * M_OUT + m] = acc[j] + V_b[m];
        }
    }
}

extern "C" void kernel_launch(void* const* d_in, const int* in_sizes, int n_in,
                              void* d_out, int out_size, void* d_ws, size_t ws_size,
                              hipStream_t stream) {
    const float* x   = (const float*)d_in[0];
    const float* a0  = (const float*)d_in[1];
    const float* U_w = (const float*)d_in[2];
    const float* U_b = (const float*)d_in[3];
    const float* W_w = (const float*)d_in[4];
    const float* W_b = (const float*)d_in[5];
    const float* V_w = (const float*)d_in[6];
    const float* V_b = (const float*)d_in[7];
    float* out = (float*)d_out;

    hipLaunchKernelGGL(elman_kernel, dim3(4096 / 16), dim3(256), 0, stream,
                       x, a0, U_w, U_b, W_w, W_b, V_w, V_b, out);
}